// Round 11
// baseline (552.929 us; speedup 1.0000x reference)
//
#include <hip/hip_runtime.h>
#include <hip/hip_cooperative_groups.h>

namespace cg = cooperative_groups;

// B=2, S=2048, H=1024, NH=16, HD=64. f32 in/out; bf16 intermediates + MFMA.
// MFMA 16x16x32 bf16 layouts (m89/m91):
//   A: lane holds A[m=lane&15][k=quad*8+j]   B: B[k=quad*8+j][n=lane&15]
//   C/D: lane reg r -> row=quad*4+r, col=lane&15
typedef __bf16 bf16;
typedef __bf16 bf16x4 __attribute__((ext_vector_type(4)));
typedef __bf16 bf16x8 __attribute__((ext_vector_type(8)));
typedef float floatx4 __attribute__((ext_vector_type(4)));

#define MFMA16(a, b, c) __builtin_amdgcn_mfma_f32_16x16x32_bf16(a, b, c, 0, 0, 0)

__device__ __forceinline__ void load_lds16(const void* g, void* l) {
    __builtin_amdgcn_global_load_lds(
        (const __attribute__((address_space(1))) unsigned int*)g,
        (__attribute__((address_space(3))) unsigned int*)l, 16, 0, 0);
}

__device__ __forceinline__ bf16x8 scale8(bf16x8 a, float s) {
    bf16x8 o;
    #pragma unroll
    for (int i = 0; i < 8; i++) o[i] = (bf16)((float)a[i] * s);
    return o;
}

struct SmemGemm { bf16 As[128][64]; bf16 Bs[128][64]; };            // 32768 B
struct SmemAttn { bf16 Ks[64][64]; bf16 Vt[64][64]; bf16 Ps[4][16][72]; }; // 25600 B

// ===========================================================================
// Device-level phase bodies (shared by mega-kernel and fallback kernels)
// ===========================================================================

// ---- cvt: x (1M f4) + Wq/Wk/Wv/Wo (256K f4 each) f32 -> bf16, grid-stride
__device__ __forceinline__ void dev_cvt(
    int nthreads, int tidg,
    const float* __restrict__ x, const float* __restrict__ wq,
    const float* __restrict__ wk, const float* __restrict__ wv,
    const float* __restrict__ wo,
    bf16* __restrict__ xb, bf16* __restrict__ wqb, bf16* __restrict__ wkb,
    bf16* __restrict__ wvb, bf16* __restrict__ wob)
{
    for (int c = tidg; c < 2097152; c += nthreads) {
        const float* src; bf16* dst; int off;
        if (c < 1048576) { src = x; dst = xb; off = c; }
        else {
            int r = c - 1048576;
            int wsel = r >> 18;              // 262144 f4 per W
            off = r & 262143;
            src = (wsel == 0) ? wq : (wsel == 1) ? wk : (wsel == 2) ? wv : wo;
            dst = (wsel == 0) ? wqb : (wsel == 1) ? wkb : (wsel == 2) ? wvb : wob;
        }
        float4 v = ((const float4*)src)[off];
        bf16x4 o;
        o[0] = (bf16)v.x; o[1] = (bf16)v.y; o[2] = (bf16)v.z; o[3] = (bf16)v.w;
        ((bf16x4*)dst)[off] = o;
    }
}

// ---- QKV GEMM tile (128x128, BK=64) + bias + fused RoPE + transposed V
__device__ __forceinline__ void dev_gemm_qkv(
    int mi, int ni, SmemGemm* sm,
    const bf16* __restrict__ xb,
    const bf16* __restrict__ Wq, const bf16* __restrict__ Wk,
    const bf16* __restrict__ Wv,
    const float* __restrict__ bq, const float* __restrict__ bk,
    const float* __restrict__ bv,
    bf16* __restrict__ q_ws, bf16* __restrict__ k_ws, bf16* __restrict__ vt_ws)
{
    int m0 = mi * 128;
    int n0 = ni * 128;
    int sec = n0 >> 10;
    int nw0 = n0 & 1023;
    const bf16* W     = (sec == 0) ? Wq : (sec == 1) ? Wk : Wv;
    const float* bias = (sec == 0) ? bq : (sec == 1) ? bk : bv;

    int tid = threadIdx.x;
    int lane = tid & 63, w = tid >> 6;
    int l15 = lane & 15, quad = lane >> 4;
    int wm = (w >> 1) * 64, wn = (w & 1) * 64;

    floatx4 acc[4][4];
    #pragma unroll
    for (int i = 0; i < 4; i++)
        #pragma unroll
        for (int j = 0; j < 4; j++) acc[i][j] = (floatx4){0.f, 0.f, 0.f, 0.f};

    for (int k0 = 0; k0 < 1024; k0 += 64) {
        __syncthreads();
        #pragma unroll
        for (int t = 0; t < 4; t++) {
            int R0 = w * 32 + t * 8;
            int row = R0 + (lane >> 3);
            int gc = (lane & 7) ^ (row & 7);
            load_lds16(&xb[(size_t)(m0 + row) * 1024 + k0 + gc * 8], &sm->As[R0][0]);
            load_lds16(&W[(size_t)(nw0 + row) * 1024 + k0 + gc * 8], &sm->Bs[R0][0]);
        }
        __syncthreads();
        #pragma unroll
        for (int kk = 0; kk < 2; kk++) {
            int cb = kk * 4 + quad;
            bf16x8 af[4], bfr[4];
            #pragma unroll
            for (int mt = 0; mt < 4; mt++) {
                int row = wm + mt * 16 + l15;
                af[mt] = *(const bf16x8*)&sm->As[row][(cb ^ (row & 7)) * 8];
            }
            #pragma unroll
            for (int nt = 0; nt < 4; nt++) {
                int row = wn + nt * 16 + l15;
                bfr[nt] = *(const bf16x8*)&sm->Bs[row][(cb ^ (row & 7)) * 8];
            }
            #pragma unroll
            for (int mt = 0; mt < 4; mt++)
                #pragma unroll
                for (int nt = 0; nt < 4; nt++)
                    acc[mt][nt] = MFMA16(af[mt], bfr[nt], acc[mt][nt]);
        }
    }

    if (sec < 2) {
        bf16* outp = (sec == 0) ? q_ws : k_ws;
        float inv[2];
        inv[0] = __expf(-(float)l15 * (9.210340371976184f / 32.0f));
        inv[1] = __expf(-(float)(16 + l15) * (9.210340371976184f / 32.0f));
        #pragma unroll
        for (int mt = 0; mt < 4; mt++) {
            #pragma unroll
            for (int r = 0; r < 4; r++) {
                int m = m0 + wm + mt * 16 + quad * 4 + r;
                int bb = m >> 11, s = m & 2047;
                #pragma unroll
                for (int nt = 0; nt < 2; nt++) {
                    int nl1 = nw0 + wn + nt * 16 + l15;
                    int nl2 = nl1 + 32;
                    float x1 = acc[mt][nt][r] + bias[nl1];
                    float x2 = acc[mt][nt + 2][r] + bias[nl2];
                    float ang = (float)s * inv[nt];
                    float sn, cs;
                    __sincosf(ang, &sn, &cs);
                    int hh = nl1 >> 6, d = nl1 & 63;
                    size_t base = ((size_t)(bb * 16 + hh) * 2048 + s) * 64;
                    outp[base + d]      = (bf16)(x1 * cs - x2 * sn);
                    outp[base + d + 32] = (bf16)(x2 * cs + x1 * sn);
                }
            }
        }
    } else {
        #pragma unroll
        for (int mt = 0; mt < 4; mt++) {
            int mbase = m0 + wm + mt * 16 + quad * 4;
            int bb = mbase >> 11, s0 = mbase & 2047;
            #pragma unroll
            for (int nt = 0; nt < 4; nt++) {
                int nl = nw0 + wn + nt * 16 + l15;
                int hh = nl >> 6, d = nl & 63;
                bf16x4 pk;
                #pragma unroll
                for (int r = 0; r < 4; r++) pk[r] = (bf16)(acc[mt][nt][r] + bias[nl]);
                *(bf16x4*)&vt_ws[((size_t)(bb * 16 + hh) * 64 + d) * 2048 + s0] = pk;
            }
        }
    }
}

// ---- attention tile (R8 structure: LDS-staged K/V, fixed-max exp2 softmax)
__device__ __forceinline__ void dev_attn(
    int xi, int h, int bb, SmemAttn* sm,
    const bf16* __restrict__ q_ws, const bf16* __restrict__ k_ws,
    const bf16* __restrict__ vt_ws, bf16* __restrict__ o_ws)
{
    int tid = threadIdx.x;
    int w = tid >> 6, lane = tid & 63;
    int l15 = lane & 15, quad = lane >> 4;
    int qt = ((h < 8) == (bb == 0)) ? xi : 31 - xi;   // 4-group balance
    int bh = bb * 16 + h;
    const bf16* qp = q_ws + (size_t)bh * 2048 * 64;
    const bf16* kp = k_ws + (size_t)bh * 2048 * 64;
    const bf16* vp = vt_ws + (size_t)bh * 64 * 2048;
    int qrow = qt * 64 + w * 16;

    const float SCL = 0.125f * 1.4426950408889634f;
    bf16x8 qf0 = scale8(*(const bf16x8*)&qp[(size_t)(qrow + l15) * 64 + quad * 8], SCL);
    bf16x8 qf1 = scale8(*(const bf16x8*)&qp[(size_t)(qrow + l15) * 64 + 32 + quad * 8], SCL);

    const float MFIX = 20.0f;
    float l_lane = 0.f;
    floatx4 acc[4];
    #pragma unroll
    for (int nt = 0; nt < 4; nt++) acc[nt] = (floatx4){0.f, 0.f, 0.f, 0.f};

    int g0 = (w * 2) * 64 + lane;
    int g1 = (w * 2 + 1) * 64 + lane;
    int r0 = g0 >> 3, c0 = (g0 & 7) ^ (r0 & 7);
    int r1 = g1 >> 3, c1 = (g1 & 7) ^ (r1 & 7);
    bf16* ksBase0 = &sm->Ks[0][0] + (w * 2) * 512;
    bf16* ksBase1 = &sm->Ks[0][0] + (w * 2 + 1) * 512;
    bf16* vtBase0 = &sm->Vt[0][0] + (w * 2) * 512;
    bf16* vtBase1 = &sm->Vt[0][0] + (w * 2 + 1) * 512;

    for (int kt = 0; kt <= qt; kt++) {
        int kt0 = kt * 64;
        __syncthreads();
        load_lds16(&kp[(size_t)(kt0 + r0) * 64 + c0 * 8], ksBase0);
        load_lds16(&kp[(size_t)(kt0 + r1) * 64 + c1 * 8], ksBase1);
        load_lds16(&vp[(size_t)r0 * 2048 + kt0 + c0 * 8], vtBase0);
        load_lds16(&vp[(size_t)r1 * 2048 + kt0 + c1 * 8], vtBase1);
        __syncthreads();

        floatx4 st[4];
        #pragma unroll
        for (int kb = 0; kb < 4; kb++) {
            int row = kb * 16 + l15;
            int rx = row & 7;
            bf16x8 a0 = *(const bf16x8*)&sm->Ks[row][(quad ^ rx) * 8];
            bf16x8 a1 = *(const bf16x8*)&sm->Ks[row][((quad + 4) ^ rx) * 8];
            floatx4 z = {0.f, 0.f, 0.f, 0.f};
            z = MFMA16(a0, qf0, z);
            z = MFMA16(a1, qf1, z);
            st[kb] = z;
        }
        if (kt0 + 63 > qrow) {
            int q = qrow + l15;
            #pragma unroll
            for (int kb = 0; kb < 4; kb++)
                #pragma unroll
                for (int r = 0; r < 4; r++) {
                    int key = kt0 + kb * 16 + quad * 4 + r;
                    if (key > q) st[kb][r] = -1e30f;
                }
        }

        #pragma unroll
        for (int kb = 0; kb < 4; kb++) {
            bf16x4 pk;
            #pragma unroll
            for (int r = 0; r < 4; r++) {
                float pv = exp2f(st[kb][r] - MFIX);
                l_lane += pv;
                pk[r] = (bf16)pv;
            }
            *(bf16x4*)&sm->Ps[w][l15][kb * 16 + quad * 4] = pk;
        }

        bf16x8 pb0 = *(const bf16x8*)&sm->Ps[w][l15][quad * 8];
        bf16x8 pb1 = *(const bf16x8*)&sm->Ps[w][l15][32 + quad * 8];
        #pragma unroll
        for (int nt = 0; nt < 4; nt++) {
            int row = nt * 16 + l15;
            int rx = row & 7;
            bf16x8 v0 = *(const bf16x8*)&sm->Vt[row][(quad ^ rx) * 8];
            bf16x8 v1 = *(const bf16x8*)&sm->Vt[row][((quad + 4) ^ rx) * 8];
            acc[nt] = MFMA16(v0, pb0, acc[nt]);
            acc[nt] = MFMA16(v1, pb1, acc[nt]);
        }
    }

    l_lane += __shfl_xor(l_lane, 16, 64);
    l_lane += __shfl_xor(l_lane, 32, 64);
    float inv = 1.f / l_lane;
    int s = qrow + l15;
    #pragma unroll
    for (int nt = 0; nt < 4; nt++) {
        bf16x4 pk;
        #pragma unroll
        for (int r = 0; r < 4; r++) pk[r] = (bf16)(acc[nt][r] * inv);
        *(bf16x4*)&o_ws[((size_t)(bb * 2048 + s)) * 1024 + h * 64 + nt * 16 + quad * 4] = pk;
    }
}

// ---- output-projection GEMM tile (128x128, BK=64) + bias, f32 out
__device__ __forceinline__ void dev_gemm_out(
    int mi, int ni, SmemGemm* sm,
    const bf16* __restrict__ A, const bf16* __restrict__ W,
    const float* __restrict__ bias, float* __restrict__ out)
{
    int m0 = mi * 128;
    int n0 = ni * 128;

    int tid = threadIdx.x;
    int lane = tid & 63, w = tid >> 6;
    int l15 = lane & 15, quad = lane >> 4;
    int wm = (w >> 1) * 64, wn = (w & 1) * 64;

    floatx4 acc[4][4];
    #pragma unroll
    for (int i = 0; i < 4; i++)
        #pragma unroll
        for (int j = 0; j < 4; j++) acc[i][j] = (floatx4){0.f, 0.f, 0.f, 0.f};

    for (int k0 = 0; k0 < 1024; k0 += 64) {
        __syncthreads();
        #pragma unroll
        for (int t = 0; t < 4; t++) {
            int R0 = w * 32 + t * 8;
            int row = R0 + (lane >> 3);
            int gc = (lane & 7) ^ (row & 7);
            load_lds16(&A[(size_t)(m0 + row) * 1024 + k0 + gc * 8], &sm->As[R0][0]);
            load_lds16(&W[(size_t)(n0 + row) * 1024 + k0 + gc * 8], &sm->Bs[R0][0]);
        }
        __syncthreads();
        #pragma unroll
        for (int kk = 0; kk < 2; kk++) {
            int cb = kk * 4 + quad;
            bf16x8 af[4], bfr[4];
            #pragma unroll
            for (int mt = 0; mt < 4; mt++) {
                int row = wm + mt * 16 + l15;
                af[mt] = *(const bf16x8*)&sm->As[row][(cb ^ (row & 7)) * 8];
            }
            #pragma unroll
            for (int nt = 0; nt < 4; nt++) {
                int row = wn + nt * 16 + l15;
                bfr[nt] = *(const bf16x8*)&sm->Bs[row][(cb ^ (row & 7)) * 8];
            }
            #pragma unroll
            for (int mt = 0; mt < 4; mt++)
                #pragma unroll
                for (int nt = 0; nt < 4; nt++)
                    acc[mt][nt] = MFMA16(af[mt], bfr[nt], acc[mt][nt]);
        }
    }

    #pragma unroll
    for (int mt = 0; mt < 4; mt++) {
        #pragma unroll
        for (int r = 0; r < 4; r++) {
            int m = m0 + wm + mt * 16 + quad * 4 + r;
            #pragma unroll
            for (int nt = 0; nt < 4; nt++) {
                int nl = n0 + wn + nt * 16 + l15;
                out[(size_t)m * 1024 + nl] = acc[mt][nt][r] + bias[nl];
            }
        }
    }
}

// ===========================================================================
// COOPERATIVE MEGA-KERNEL: cvt -> qkv(+RoPE) -> attn -> out, grid.sync()
// between phases. Grid 1024 x 256, 4 blocks/CU (32KB LDS, VGPR<=128).
// Block->CU round-robin gives: phase1 = 3 jobs/CU; phase2 = the 4-group
// {(x,h,b),(x,h+8,b),(x,h,b+1),(x,h+8,b+1)} qt-balance; phase3 = 1 job/CU.
// ===========================================================================
__global__ __launch_bounds__(256, 4) void mha_mega(
    const float* __restrict__ x,
    const float* __restrict__ Wq, const float* __restrict__ bq,
    const float* __restrict__ Wk, const float* __restrict__ bk,
    const float* __restrict__ Wv, const float* __restrict__ bv,
    const float* __restrict__ Wo, const float* __restrict__ bo,
    float* __restrict__ out,
    bf16* __restrict__ xb, bf16* __restrict__ q_ws, bf16* __restrict__ k_ws,
    bf16* __restrict__ vt_ws,
    bf16* __restrict__ wqb, bf16* __restrict__ wkb, bf16* __restrict__ wvb,
    bf16* __restrict__ wob)
{
    __shared__ __align__(16) char smem[sizeof(SmemGemm)];
    cg::grid_group grid = cg::this_grid();
    int bid = blockIdx.x;

    // P0: convert x + all W to bf16
    dev_cvt(1024 * 256, bid * 256 + (int)threadIdx.x,
            x, Wq, Wk, Wv, Wo, xb, wqb, wkb, wvb, wob);
    grid.sync();

    // P1: QKV projection (768 jobs; blocks 768..1023 idle -> 3 jobs/CU)
    if (bid < 768)
        dev_gemm_qkv(bid & 31, bid >> 5, (SmemGemm*)smem,
                     xb, wqb, wkb, wvb, bq, bk, bv, q_ws, k_ws, vt_ws);
    grid.sync();

    // P2: attention (1024 jobs; o_ws aliases xb, dead after P1)
    dev_attn(bid & 31, (bid >> 5) & 15, bid >> 9, (SmemAttn*)smem,
             q_ws, k_ws, vt_ws, xb);
    grid.sync();

    // P3: output projection (256 jobs -> 1/CU)
    if (bid < 256)
        dev_gemm_out(bid & 31, bid >> 5, (SmemGemm*)smem, xb, wob, bo, out);
}

// ===========================================================================
// FALLBACK standalone kernels (same device bodies)
// ===========================================================================
__global__ __launch_bounds__(256) void cvt_all_kernel(
    const float* x, const float* wq, const float* wk, const float* wv,
    const float* wo, bf16* xb, bf16* wqb, bf16* wkb, bf16* wvb, bf16* wob)
{
    dev_cvt(gridDim.x * 256, blockIdx.x * 256 + (int)threadIdx.x,
            x, wq, wk, wv, wo, xb, wqb, wkb, wvb, wob);
}

__global__ __launch_bounds__(256) void gemm_qkv_fast(
    const bf16* xb, const bf16* Wq, const bf16* Wk, const bf16* Wv,
    const float* bq, const float* bk, const float* bv,
    bf16* q_ws, bf16* k_ws, bf16* vt_ws)
{
    __shared__ SmemGemm sm;
    dev_gemm_qkv(blockIdx.x, blockIdx.y, &sm, xb, Wq, Wk, Wv, bq, bk, bv,
                 q_ws, k_ws, vt_ws);
}

__global__ __launch_bounds__(256) void attn_kernel(
    const bf16* q_ws, const bf16* k_ws, const bf16* vt_ws, bf16* o_ws)
{
    __shared__ SmemAttn sm;
    dev_attn(blockIdx.x, blockIdx.y, blockIdx.z, &sm, q_ws, k_ws, vt_ws, o_ws);
}

__global__ __launch_bounds__(256) void gemm_out_fast(
    const bf16* A, const bf16* W, const float* bias, float* out)
{
    __shared__ SmemGemm sm;
    dev_gemm_out(blockIdx.x, blockIdx.y, &sm, A, W, bias, out);
}

// ---- f32-weight fallback (ws too small for bf16 weight copies)
__global__ __launch_bounds__(256) void gemm_qkv_f32w(
    const bf16* __restrict__ xb,
    const float* __restrict__ Wq, const float* __restrict__ Wk,
    const float* __restrict__ Wv,
    const float* __restrict__ bq, const float* __restrict__ bk,
    const float* __restrict__ bv,
    bf16* __restrict__ q_ws, bf16* __restrict__ k_ws, bf16* __restrict__ vt_ws)
{
    int m0 = blockIdx.x * 128;
    int n0 = blockIdx.y * 128;
    int sec = n0 >> 10;
    int nw0 = n0 & 1023;
    const float* W    = (sec == 0) ? Wq : (sec == 1) ? Wk : Wv;
    const float* bias = (sec == 0) ? bq : (sec == 1) ? bk : bv;

    __shared__ bf16 As[128][72];
    __shared__ bf16 Bs[128][72];

    int tid = threadIdx.x;
    int lane = tid & 63, w = tid >> 6;
    int l15 = lane & 15, quad = lane >> 4;
    int wm = (w >> 1) * 64, wn = (w & 1) * 64;
    int sr = tid >> 1;
    int sk = (tid & 1) * 32;

    floatx4 acc[4][4];
    #pragma unroll
    for (int i = 0; i < 4; i++)
        #pragma unroll
        for (int j = 0; j < 4; j++) acc[i][j] = (floatx4){0.f, 0.f, 0.f, 0.f};

    for (int k0 = 0; k0 < 1024; k0 += 64) {
        __syncthreads();
        const bf16* ap = &xb[(size_t)(m0 + sr) * 1024 + k0 + sk];
        bf16x8 a0 = *(const bf16x8*)(ap);
        bf16x8 a1 = *(const bf16x8*)(ap + 8);
        bf16x8 a2 = *(const bf16x8*)(ap + 16);
        bf16x8 a3 = *(const bf16x8*)(ap + 24);
        const float* wp = &W[(size_t)(nw0 + sr) * 1024 + k0 + sk];
        bf16x8 bv_[4];
        #pragma unroll
        for (int c = 0; c < 4; c++) {
            float4 f0 = *(const float4*)(wp + c * 8);
            float4 f1 = *(const float4*)(wp + c * 8 + 4);
            bf16x8 t;
            t[0] = (bf16)f0.x; t[1] = (bf16)f0.y; t[2] = (bf16)f0.z; t[3] = (bf16)f0.w;
            t[4] = (bf16)f1.x; t[5] = (bf16)f1.y; t[6] = (bf16)f1.z; t[7] = (bf16)f1.w;
            bv_[c] = t;
        }
        *(bf16x8*)&As[sr][sk + 0]  = a0;
        *(bf16x8*)&As[sr][sk + 8]  = a1;
        *(bf16x8*)&As[sr][sk + 16] = a2;
        *(bf16x8*)&As[sr][sk + 24] = a3;
        #pragma unroll
        for (int c = 0; c < 4; c++) *(bf16x8*)&Bs[sr][sk + c * 8] = bv_[c];
        __syncthreads();
        #pragma unroll
        for (int kk = 0; kk < 64; kk += 32) {
            bf16x8 af[4], bfr[4];
            #pragma unroll
            for (int mt = 0; mt < 4; mt++)
                af[mt] = *(const bf16x8*)&As[wm + mt * 16 + l15][kk + quad * 8];
            #pragma unroll
            for (int nt = 0; nt < 4; nt++)
                bfr[nt] = *(const bf16x8*)&Bs[wn + nt * 16 + l15][kk + quad * 8];
            #pragma unroll
            for (int mt = 0; mt < 4; mt++)
                #pragma unroll
                for (int nt = 0; nt < 4; nt++)
                    acc[mt][nt] = MFMA16(af[mt], bfr[nt], acc[mt][nt]);
        }
    }

    if (sec < 2) {
        bf16* outp = (sec == 0) ? q_ws : k_ws;
        float inv[2];
        inv[0] = __expf(-(float)l15 * (9.210340371976184f / 32.0f));
        inv[1] = __expf(-(float)(16 + l15) * (9.210340371976184f / 32.0f));
        #pragma unroll
        for (int mt = 0; mt < 4; mt++) {
            #pragma unroll
            for (int r = 0; r < 4; r++) {
                int m = m0 + wm + mt * 16 + quad * 4 + r;
                int bb = m >> 11, s = m & 2047;
                #pragma unroll
                for (int nt = 0; nt < 2; nt++) {
                    int nl1 = nw0 + wn + nt * 16 + l15;
                    int nl2 = nl1 + 32;
                    float x1 = acc[mt][nt][r] + bias[nl1];
                    float x2 = acc[mt][nt + 2][r] + bias[nl2];
                    float ang = (float)s * inv[nt];
                    float sn, cs;
                    __sincosf(ang, &sn, &cs);
                    int hh = nl1 >> 6, d = nl1 & 63;
                    size_t base = ((size_t)(bb * 16 + hh) * 2048 + s) * 64;
                    outp[base + d]      = (bf16)(x1 * cs - x2 * sn);
                    outp[base + d + 32] = (bf16)(x2 * cs + x1 * sn);
                }
            }
        }
    } else {
        #pragma unroll
        for (int mt = 0; mt < 4; mt++) {
            int mbase = m0 + wm + mt * 16 + quad * 4;
            int bb = mbase >> 11, s0 = mbase & 2047;
            #pragma unroll
            for (int nt = 0; nt < 4; nt++) {
                int nl = nw0 + wn + nt * 16 + l15;
                int hh = nl >> 6, d = nl & 63;
                bf16x4 pk;
                #pragma unroll
                for (int r = 0; r < 4; r++) pk[r] = (bf16)(acc[mt][nt][r] + bias[nl]);
                *(bf16x4*)&vt_ws[((size_t)(bb * 16 + hh) * 64 + d) * 2048 + s0] = pk;
            }
        }
    }
}

__global__ __launch_bounds__(256) void gemm_out_f32w(
    const bf16* __restrict__ A, const float* __restrict__ W,
    const float* __restrict__ bias, float* __restrict__ out)
{
    int m0 = blockIdx.x * 128;
    int n0 = blockIdx.y * 128;

    __shared__ bf16 As[128][72];
    __shared__ bf16 Bs[128][72];

    int tid = threadIdx.x;
    int lane = tid & 63, w = tid >> 6;
    int l15 = lane & 15, quad = lane >> 4;
    int wm = (w >> 1) * 64, wn = (w & 1) * 64;
    int sr = tid >> 1;
    int sk = (tid & 1) * 32;

    floatx4 acc[4][4];
    #pragma unroll
    for (int i = 0; i < 4; i++)
        #pragma unroll
        for (int j = 0; j < 4; j++) acc[i][j] = (floatx4){0.f, 0.f, 0.f, 0.f};

    for (int k0 = 0; k0 < 1024; k0 += 64) {
        __syncthreads();
        const bf16* ap = &A[(size_t)(m0 + sr) * 1024 + k0 + sk];
        bf16x8 a0 = *(const bf16x8*)(ap);
        bf16x8 a1 = *(const bf16x8*)(ap + 8);
        bf16x8 a2 = *(const bf16x8*)(ap + 16);
        bf16x8 a3 = *(const bf16x8*)(ap + 24);
        const float* wp = &W[(size_t)(n0 + sr) * 1024 + k0 + sk];
        bf16x8 bv_[4];
        #pragma unroll
        for (int c = 0; c < 4; c++) {
            float4 f0 = *(const float4*)(wp + c * 8);
            float4 f1 = *(const float4*)(wp + c * 8 + 4);
            bf16x8 t;
            t[0] = (bf16)f0.x; t[1] = (bf16)f0.y; t[2] = (bf16)f0.z; t[3] = (bf16)f0.w;
            t[4] = (bf16)f1.x; t[5] = (bf16)f1.y; t[6] = (bf16)f1.z; t[7] = (bf16)f1.w;
            bv_[c] = t;
        }
        *(bf16x8*)&As[sr][sk + 0]  = a0;
        *(bf16x8*)&As[sr][sk + 8]  = a1;
        *(bf16x8*)&As[sr][sk + 16] = a2;
        *(bf16x8*)&As[sr][sk + 24] = a3;
        #pragma unroll
        for (int c = 0; c < 4; c++) *(bf16x8*)&Bs[sr][sk + c * 8] = bv_[c];
        __syncthreads();
        #pragma unroll
        for (int kk = 0; kk < 64; kk += 32) {
            bf16x8 af[4], bfr[4];
            #pragma unroll
            for (int mt = 0; mt < 4; mt++)
                af[mt] = *(const bf16x8*)&As[wm + mt * 16 + l15][kk + quad * 8];
            #pragma unroll
            for (int nt = 0; nt < 4; nt++)
                bfr[nt] = *(const bf16x8*)&Bs[wn + nt * 16 + l15][kk + quad * 8];
            #pragma unroll
            for (int mt = 0; mt < 4; mt++)
                #pragma unroll
                for (int nt = 0; nt < 4; nt++)
                    acc[mt][nt] = MFMA16(af[mt], bfr[nt], acc[mt][nt]);
        }
    }

    #pragma unroll
    for (int mt = 0; mt < 4; mt++) {
        #pragma unroll
        for (int r = 0; r < 4; r++) {
            int m = m0 + wm + mt * 16 + quad * 4 + r;
            #pragma unroll
            for (int nt = 0; nt < 4; nt++) {
                int nl = n0 + wn + nt * 16 + l15;
                out[(size_t)m * 1024 + nl] = acc[mt][nt][r] + bias[nl];
            }
        }
    }
}

// ---------------------------------------------------------------------------
extern "C" void kernel_launch(void* const* d_in, const int* in_sizes, int n_in,
                              void* d_out, int out_size, void* d_ws, size_t ws_size,
                              hipStream_t stream) {
    const float* x  = (const float*)d_in[0];
    const float* Wq = (const float*)d_in[1];
    const float* bq = (const float*)d_in[2];
    const float* Wk = (const float*)d_in[3];
    const float* bk = (const float*)d_in[4];
    const float* Wv = (const float*)d_in[5];
    const float* bv = (const float*)d_in[6];
    const float* Wo = (const float*)d_in[7];
    const float* bo = (const float*)d_in[8];
    float* out = (float*)d_out;

    const size_t NELEM = (size_t)2 * 2048 * 1024;   // 4,194,304
    const size_t WELEM = (size_t)1024 * 1024;
    bf16* xb    = (bf16*)d_ws;          // 8MB; reused as o_ws after qkv
    bf16* q_ws  = xb + NELEM;
    bf16* k_ws  = q_ws + NELEM;
    bf16* vt_ws = k_ws + NELEM;         // (B,NH,HD,S)
    bf16* o_ws  = xb;
    bf16* wqb   = vt_ws + NELEM;        // +2MB each
    bf16* wkb   = wqb + WELEM;
    bf16* wvb   = wkb + WELEM;
    bf16* wob   = wvb + WELEM;          // ends at 40MB

    bool fast = ws_size >= (size_t)40 * 1024 * 1024;   // constant across calls

    if (fast) {
        void* args[] = {
            (void*)&x, (void*)&Wq, (void*)&bq, (void*)&Wk, (void*)&bk,
            (void*)&Wv, (void*)&bv, (void*)&Wo, (void*)&bo, (void*)&out,
            (void*)&xb, (void*)&q_ws, (void*)&k_ws, (void*)&vt_ws,
            (void*)&wqb, (void*)&wkb, (void*)&wvb, (void*)&wob };
        hipError_t e = hipLaunchCooperativeKernel(
            (const void*)mha_mega, dim3(1024), dim3(256), args, 0, stream);
        if (e != hipSuccess) {
            (void)hipGetLastError();   // clear, fall back to 4-kernel path
            cvt_all_kernel<<<1024, 256, 0, stream>>>(x, Wq, Wk, Wv, Wo,
                                                     xb, wqb, wkb, wvb, wob);
            gemm_qkv_fast<<<dim3(32, 24), 256, 0, stream>>>(
                xb, wqb, wkb, wvb, bq, bk, bv, q_ws, k_ws, vt_ws);
            attn_kernel<<<dim3(32, 16, 2), 256, 0, stream>>>(q_ws, k_ws, vt_ws, o_ws);
            gemm_out_fast<<<dim3(32, 8), 256, 0, stream>>>(o_ws, wob, bo, out);
        }
    } else {
        // minimal-ws path: convert x only, stage f32 weights in-flight
        {
            // reuse dev_cvt shape for x via cvt_all with W pointers aliased to x?
            // simpler: dedicated small conversion of x using gemm-free kernel
        }
        cvt_all_kernel<<<1024, 256, 0, stream>>>(x, Wq, Wk, Wv, Wo,
                                                 xb, xb, xb, xb, xb); // xb only matters
        gemm_qkv_f32w<<<dim3(32, 24), 256, 0, stream>>>(
            xb, Wq, Wk, Wv, bq, bk, bv, q_ws, k_ws, vt_ws);
        attn_kernel<<<dim3(32, 16, 2), 256, 0, stream>>>(q_ws, k_ws, vt_ws, o_ws);
        gemm_out_f32w<<<dim3(32, 8), 256, 0, stream>>>(o_ws, Wo, bo, out);
    }
}